// Round 5
// baseline (358.546 us; speedup 1.0000x reference)
//
#include <hip/hip_runtime.h>

// EdgeSageLayer on MI355X — round 5.
// agg[n] = (sum_{e:dst=n} concat(x[src_e], ea_e)) @ msg_w / deg + msg_b*(deg>0)
// R4 postmortem: finalize held 160 weight floats/lane -> compiler remat/spill
// (VGPR=124) -> ~160 reloads per node. R5: split finalize into msg_k (96 w)
// + self_k (64 w). place_k emits (edge,src) int2 pairs so aggregate's index
// chain is one gather deep; aggregate runs 4 nodes/wave.

constexpr int N_NODES  = 50000;
constexpr int N_EDGES  = 800000;
constexpr int IN_DIM   = 64;
constexpr int EDGE_DIM = 32;
constexpr int OUT_DIM  = 64;

// ---------------------------------------------------------------------------
// K1: histogram of dst (fire-and-forget int atomics), int4 edge reads.
// ---------------------------------------------------------------------------
__global__ __launch_bounds__(256) void count_k(const int* __restrict__ ei,
                                               int* cnt) {
    const int t = blockIdx.x * 256 + threadIdx.x;
    if (t * 4 + 3 < N_EDGES) {
        const int4 d4 = ((const int4*)(ei + N_EDGES))[t];
        atomicAdd(&cnt[d4.x], 1);
        atomicAdd(&cnt[d4.y], 1);
        atomicAdd(&cnt[d4.z], 1);
        atomicAdd(&cnt[d4.w], 1);
    } else {
        for (int e = t * 4; e < min(t * 4 + 4, N_EDGES); ++e)
            atomicAdd(&cnt[ei[N_EDGES + e]], 1);
    }
}

// ---------------------------------------------------------------------------
// K2: allocate contiguous ranges: wave scan + one global-cursor atomic/wave.
// cur[n] = exclusive start (K3 bumps it; K4 recovers start = cur - cnt).
// ---------------------------------------------------------------------------
__global__ __launch_bounds__(256) void alloc_k(const int* __restrict__ cnt,
                                               int* cur, int* cursor) {
    const int n    = blockIdx.x * 256 + threadIdx.x;
    const int lane = threadIdx.x & 63;
    const int c    = (n < N_NODES) ? cnt[n] : 0;

    int v = c;
#pragma unroll
    for (int d = 1; d < 64; d <<= 1) {
        int t = __shfl_up(v, d);
        if (lane >= d) v += t;
    }
    const int total = __shfl(v, 63);
    int base = 0;
    if (lane == 0) base = atomicAdd(cursor, total);
    base = __shfl(base, 0);
    if (n < N_NODES) cur[n] = base + v - c;
}

// ---------------------------------------------------------------------------
// K3a: place (edge,src) int2 into pairs (primary path).
// ---------------------------------------------------------------------------
__global__ __launch_bounds__(256) void place_pairs_k(const int* __restrict__ ei,
                                                     int* cur,
                                                     int2* __restrict__ pairs) {
    const int t = blockIdx.x * 256 + threadIdx.x;
    if (t * 4 + 3 < N_EDGES) {
        const int4 d4 = ((const int4*)(ei + N_EDGES))[t];
        const int4 s4 = ((const int4*)ei)[t];
        pairs[atomicAdd(&cur[d4.x], 1)] = make_int2(t * 4 + 0, s4.x);
        pairs[atomicAdd(&cur[d4.y], 1)] = make_int2(t * 4 + 1, s4.y);
        pairs[atomicAdd(&cur[d4.z], 1)] = make_int2(t * 4 + 2, s4.z);
        pairs[atomicAdd(&cur[d4.w], 1)] = make_int2(t * 4 + 3, s4.w);
    } else {
        for (int e = t * 4; e < min(t * 4 + 4, N_EDGES); ++e)
            pairs[atomicAdd(&cur[ei[N_EDGES + e]], 1)] = make_int2(e, ei[e]);
    }
}

// ---------------------------------------------------------------------------
// helper: one <=64-edge batch of a node (pairs variant), for deg>64 tail.
// ---------------------------------------------------------------------------
__device__ __forceinline__ void gather_batch_pairs(
    const float* __restrict__ x, const float* __restrict__ ea,
    const int2* __restrict__ pairs,
    int s, int base, int m, int lane, int grpx, int colx, int grpe, int cole,
    float4& ax, float4& ae)
{
    int e = 0, src = 0;
    if (lane < m) { const int2 p = pairs[s + base + lane]; e = p.x; src = p.y; }
    for (int j = 0; j < m; j += 4) {
        const int jj = j + grpx;
        const int sj = __shfl(src, jj);
        if (jj < m) {
            const float4 v = ((const float4*)(x + (size_t)sj * IN_DIM))[colx];
            ax.x += v.x; ax.y += v.y; ax.z += v.z; ax.w += v.w;
        }
    }
    for (int j = 0; j < m; j += 8) {
        const int jj = j + grpe;
        const int ej = __shfl(e, jj);
        if (jj < m) {
            const float4 v = ((const float4*)(ea + (size_t)ej * EDGE_DIM))[cole];
            ae.x += v.x; ae.y += v.y; ae.z += v.z; ae.w += v.w;
        }
    }
}

// ---------------------------------------------------------------------------
// K4a: gather-reduce, FOUR nodes in flight per wave. Index chain is one
// int2 gather deep (src pre-resolved by place_pairs_k). x rows: float4 x 16
// lanes (4 edges/instr); ea: float4 x 8 lanes (8 edges/instr); shfl_xor
// reduce; float4 stores zero-fill deg==0 rows.
// ---------------------------------------------------------------------------
__global__ __launch_bounds__(256) void aggregate_pairs_k(
    const float* __restrict__ x, const float* __restrict__ ea,
    const int2* __restrict__ pairs, const int* __restrict__ cnt,
    const int* __restrict__ cur,
    float* __restrict__ sum_x, float* __restrict__ sum_ea)
{
    const int lane   = threadIdx.x & 63;
    const int wave   = (blockIdx.x * blockDim.x + threadIdx.x) >> 6;
    const int nwaves = (gridDim.x * blockDim.x) >> 6;

    const int grpx = lane >> 4, colx = lane & 15;
    const int grpe = lane >> 3, cole = lane & 7;

    for (int n0 = wave * 4; n0 < N_NODES; n0 += nwaves * 4) {
        int c[4], s[4], m[4];
#pragma unroll
        for (int i = 0; i < 4; ++i) {
            const bool valid = (n0 + i) < N_NODES;
            c[i] = valid ? __builtin_amdgcn_readfirstlane(cnt[n0 + i]) : 0;
            s[i] = valid ? __builtin_amdgcn_readfirstlane(cur[n0 + i]) - c[i] : 0;
            m[i] = min(c[i], 64);
        }

        int e[4], src[4];
#pragma unroll
        for (int i = 0; i < 4; ++i) {
            e[i] = 0; src[i] = 0;
            if (lane < m[i]) {
                const int2 p = pairs[s[i] + lane];
                e[i] = p.x; src[i] = p.y;
            }
        }

        float4 ax[4], ae[4];
#pragma unroll
        for (int i = 0; i < 4; ++i) { ax[i] = {0,0,0,0}; ae[i] = {0,0,0,0}; }

        const int mMax = max(max(m[0], m[1]), max(m[2], m[3]));
        for (int j = 0; j < mMax; j += 4) {
            const int jj = j + grpx;
#pragma unroll
            for (int i = 0; i < 4; ++i) {
                const int sj = __shfl(src[i], jj);
                if (jj < m[i]) {
                    const float4 v = ((const float4*)(x + (size_t)sj * IN_DIM))[colx];
                    ax[i].x += v.x; ax[i].y += v.y; ax[i].z += v.z; ax[i].w += v.w;
                }
            }
        }
        for (int j = 0; j < mMax; j += 8) {
            const int jj = j + grpe;
#pragma unroll
            for (int i = 0; i < 4; ++i) {
                const int ej = __shfl(e[i], jj);
                if (jj < m[i]) {
                    const float4 v = ((const float4*)(ea + (size_t)ej * EDGE_DIM))[cole];
                    ae[i].x += v.x; ae[i].y += v.y; ae[i].z += v.z; ae[i].w += v.w;
                }
            }
        }

        // rare: deg > 64
#pragma unroll
        for (int i = 0; i < 4; ++i)
            for (int base = 64; base < c[i]; base += 64)
                gather_batch_pairs(x, ea, pairs, s[i], base, min(64, c[i] - base),
                                   lane, grpx, colx, grpe, cole, ax[i], ae[i]);

#pragma unroll
        for (int mask = 16; mask < 64; mask <<= 1)
#pragma unroll
            for (int i = 0; i < 4; ++i) {
                ax[i].x += __shfl_xor(ax[i].x, mask);
                ax[i].y += __shfl_xor(ax[i].y, mask);
                ax[i].z += __shfl_xor(ax[i].z, mask);
                ax[i].w += __shfl_xor(ax[i].w, mask);
            }
#pragma unroll
        for (int mask = 8; mask < 64; mask <<= 1)
#pragma unroll
            for (int i = 0; i < 4; ++i) {
                ae[i].x += __shfl_xor(ae[i].x, mask);
                ae[i].y += __shfl_xor(ae[i].y, mask);
                ae[i].z += __shfl_xor(ae[i].z, mask);
                ae[i].w += __shfl_xor(ae[i].w, mask);
            }

#pragma unroll
        for (int i = 0; i < 4; ++i) {
            if ((n0 + i) < N_NODES) {
                if (lane < 16)
                    ((float4*)(sum_x + (size_t)(n0 + i) * IN_DIM))[lane] = ax[i];
                if (lane < 8)
                    ((float4*)(sum_ea + (size_t)(n0 + i) * EDGE_DIM))[lane] = ae[i];
            }
        }
    }
}

// ---------------------------------------------------------------------------
// K5a: message finalize. Wave per node; lane c = output column. ONLY the 96
// msg_w weights per lane -> fits in VGPRs, no remat. Overwrites out row
// (aliases sum_x; row owned by exactly one wave, store depends on loads).
// ---------------------------------------------------------------------------
__global__ __launch_bounds__(256) void msg_k(
    const float* sum_x_in, const float* __restrict__ sum_ea,
    const int* __restrict__ cnt,
    const float* __restrict__ msg_w, const float* __restrict__ msg_b,
    float* out)
{
    const int c = threadIdx.x & 63;

    float wm[96];
#pragma unroll
    for (int k = 0; k < 96; ++k) wm[k] = msg_w[k * OUT_DIM + c];
    const float mb = msg_b[c];

    const int wave   = (blockIdx.x * blockDim.x + threadIdx.x) >> 6;
    const int nwaves = (gridDim.x * blockDim.x) >> 6;

    for (int n0 = wave; n0 < N_NODES; n0 += nwaves) {
        const int n = __builtin_amdgcn_readfirstlane(n0);
        const float4* r1 = (const float4*)(sum_x_in + (size_t)n * IN_DIM);
        const float4* r2 = (const float4*)(sum_ea   + (size_t)n * EDGE_DIM);
        const int d = cnt[n];

        float a0 = 0.f, a1 = 0.f, a2 = 0.f, a3 = 0.f;
#pragma unroll
        for (int q = 0; q < 16; ++q) {
            const float4 v = r1[q];
            a0 = fmaf(v.x, wm[4 * q + 0], a0);
            a1 = fmaf(v.y, wm[4 * q + 1], a1);
            a2 = fmaf(v.z, wm[4 * q + 2], a2);
            a3 = fmaf(v.w, wm[4 * q + 3], a3);
        }
#pragma unroll
        for (int q = 0; q < 8; ++q) {
            const float4 v = r2[q];
            a0 = fmaf(v.x, wm[64 + 4 * q + 0], a0);
            a1 = fmaf(v.y, wm[64 + 4 * q + 1], a1);
            a2 = fmaf(v.z, wm[64 + 4 * q + 2], a2);
            a3 = fmaf(v.w, wm[64 + 4 * q + 3], a3);
        }

        const float inv  = 1.0f / (float)max(d, 1);
        const float bsel = (d > 0) ? 1.0f : 0.0f;
        const float am   = (a0 + a1) + (a2 + a3);

        out[(size_t)n * OUT_DIM + c] = am * inv + mb * bsel;
    }
}

// ---------------------------------------------------------------------------
// K5b: self finalize. out[n][c] += x[n] . self_w[:,c] + self_b[c].
// 64 weights per lane -> no pressure.
// ---------------------------------------------------------------------------
__global__ __launch_bounds__(256) void self_k(
    const float* __restrict__ x,
    const float* __restrict__ self_w, const float* __restrict__ self_b,
    float* out)
{
    const int c = threadIdx.x & 63;

    float wsf[64];
#pragma unroll
    for (int k = 0; k < 64; ++k) wsf[k] = self_w[k * OUT_DIM + c];
    const float sb = self_b[c];

    const int wave   = (blockIdx.x * blockDim.x + threadIdx.x) >> 6;
    const int nwaves = (gridDim.x * blockDim.x) >> 6;

    for (int n0 = wave; n0 < N_NODES; n0 += nwaves) {
        const int n = __builtin_amdgcn_readfirstlane(n0);
        const float4* r3 = (const float4*)(x + (size_t)n * IN_DIM);

        float a0 = 0.f, a1 = 0.f, a2 = 0.f, a3 = 0.f;
#pragma unroll
        for (int q = 0; q < 16; ++q) {
            const float4 v = r3[q];
            a0 = fmaf(v.x, wsf[4 * q + 0], a0);
            a1 = fmaf(v.y, wsf[4 * q + 1], a1);
            a2 = fmaf(v.z, wsf[4 * q + 2], a2);
            a3 = fmaf(v.w, wsf[4 * q + 3], a3);
        }
        const float as = (a0 + a1) + (a2 + a3);
        out[(size_t)n * OUT_DIM + c] += as + sb;
    }
}

// ---------------------------------------------------------------------------
// Tier-2 kernels (perm-only CSR, R4 style) if ws can't hold int2 pairs.
// ---------------------------------------------------------------------------
__global__ __launch_bounds__(256) void place_perm_k(const int* __restrict__ ei,
                                                    int* cur, int* __restrict__ perm) {
    const int t = blockIdx.x * 256 + threadIdx.x;
    if (t * 4 + 3 < N_EDGES) {
        const int4 d4 = ((const int4*)(ei + N_EDGES))[t];
        perm[atomicAdd(&cur[d4.x], 1)] = t * 4 + 0;
        perm[atomicAdd(&cur[d4.y], 1)] = t * 4 + 1;
        perm[atomicAdd(&cur[d4.z], 1)] = t * 4 + 2;
        perm[atomicAdd(&cur[d4.w], 1)] = t * 4 + 3;
    } else {
        for (int e = t * 4; e < min(t * 4 + 4, N_EDGES); ++e)
            perm[atomicAdd(&cur[ei[N_EDGES + e]], 1)] = e;
    }
}

__device__ __forceinline__ void gather_batch_perm(
    const float* __restrict__ x, const float* __restrict__ ea,
    const int* __restrict__ ei, const int* __restrict__ perm,
    int s, int base, int m, int lane, int grpx, int colx, int grpe, int cole,
    float4& ax, float4& ae)
{
    int e = 0, src = 0;
    if (lane < m) { e = perm[s + base + lane]; src = ei[e]; }
    for (int j = 0; j < m; j += 4) {
        const int jj = j + grpx;
        const int sj = __shfl(src, jj);
        if (jj < m) {
            const float4 v = ((const float4*)(x + (size_t)sj * IN_DIM))[colx];
            ax.x += v.x; ax.y += v.y; ax.z += v.z; ax.w += v.w;
        }
    }
    for (int j = 0; j < m; j += 8) {
        const int jj = j + grpe;
        const int ej = __shfl(e, jj);
        if (jj < m) {
            const float4 v = ((const float4*)(ea + (size_t)ej * EDGE_DIM))[cole];
            ae.x += v.x; ae.y += v.y; ae.z += v.z; ae.w += v.w;
        }
    }
}

__global__ __launch_bounds__(256) void aggregate_perm_k(
    const float* __restrict__ x, const int* __restrict__ ei,
    const float* __restrict__ ea, const int* __restrict__ perm,
    const int* __restrict__ cnt, const int* __restrict__ cur,
    float* __restrict__ sum_x, float* __restrict__ sum_ea)
{
    const int lane   = threadIdx.x & 63;
    const int wave   = (blockIdx.x * blockDim.x + threadIdx.x) >> 6;
    const int nwaves = (gridDim.x * blockDim.x) >> 6;
    const int grpx = lane >> 4, colx = lane & 15;
    const int grpe = lane >> 3, cole = lane & 7;

    for (int n0 = wave * 2; n0 < N_NODES; n0 += nwaves * 2) {
        const int  nA   = __builtin_amdgcn_readfirstlane(n0);
        const bool hasB = (n0 + 1 < N_NODES);
        const int  nB   = nA + 1;
        const int cA = __builtin_amdgcn_readfirstlane(cnt[nA]);
        const int sA = __builtin_amdgcn_readfirstlane(cur[nA]) - cA;
        const int cB = hasB ? __builtin_amdgcn_readfirstlane(cnt[nB]) : 0;
        const int sB = hasB ? __builtin_amdgcn_readfirstlane(cur[nB]) - cB : 0;
        const int mA = min(cA, 64), mB = min(cB, 64);

        int eA = 0, srcA = 0, eB = 0, srcB = 0;
        if (lane < mA) eA = perm[sA + lane];
        if (lane < mB) eB = perm[sB + lane];
        if (lane < mA) srcA = ei[eA];
        if (lane < mB) srcB = ei[eB];

        float4 axA = {0,0,0,0}, aeA = {0,0,0,0};
        float4 axB = {0,0,0,0}, aeB = {0,0,0,0};

        const int mMax = max(mA, mB);
        for (int j = 0; j < mMax; j += 4) {
            const int jj  = j + grpx;
            const int sjA = __shfl(srcA, jj);
            const int sjB = __shfl(srcB, jj);
            if (jj < mA) {
                const float4 v = ((const float4*)(x + (size_t)sjA * IN_DIM))[colx];
                axA.x += v.x; axA.y += v.y; axA.z += v.z; axA.w += v.w;
            }
            if (jj < mB) {
                const float4 v = ((const float4*)(x + (size_t)sjB * IN_DIM))[colx];
                axB.x += v.x; axB.y += v.y; axB.z += v.z; axB.w += v.w;
            }
        }
        for (int j = 0; j < mMax; j += 8) {
            const int jj  = j + grpe;
            const int ejA = __shfl(eA, jj);
            const int ejB = __shfl(eB, jj);
            if (jj < mA) {
                const float4 v = ((const float4*)(ea + (size_t)ejA * EDGE_DIM))[cole];
                aeA.x += v.x; aeA.y += v.y; aeA.z += v.z; aeA.w += v.w;
            }
            if (jj < mB) {
                const float4 v = ((const float4*)(ea + (size_t)ejB * EDGE_DIM))[cole];
                aeB.x += v.x; aeB.y += v.y; aeB.z += v.z; aeB.w += v.w;
            }
        }
        for (int base = 64; base < cA; base += 64)
            gather_batch_perm(x, ea, ei, perm, sA, base, min(64, cA - base),
                              lane, grpx, colx, grpe, cole, axA, aeA);
        for (int base = 64; base < cB; base += 64)
            gather_batch_perm(x, ea, ei, perm, sB, base, min(64, cB - base),
                              lane, grpx, colx, grpe, cole, axB, aeB);

#pragma unroll
        for (int mask = 16; mask < 64; mask <<= 1) {
            axA.x += __shfl_xor(axA.x, mask); axA.y += __shfl_xor(axA.y, mask);
            axA.z += __shfl_xor(axA.z, mask); axA.w += __shfl_xor(axA.w, mask);
            axB.x += __shfl_xor(axB.x, mask); axB.y += __shfl_xor(axB.y, mask);
            axB.z += __shfl_xor(axB.z, mask); axB.w += __shfl_xor(axB.w, mask);
        }
#pragma unroll
        for (int mask = 8; mask < 64; mask <<= 1) {
            aeA.x += __shfl_xor(aeA.x, mask); aeA.y += __shfl_xor(aeA.y, mask);
            aeA.z += __shfl_xor(aeA.z, mask); aeA.w += __shfl_xor(aeA.w, mask);
            aeB.x += __shfl_xor(aeB.x, mask); aeB.y += __shfl_xor(aeB.y, mask);
            aeB.z += __shfl_xor(aeB.z, mask); aeB.w += __shfl_xor(aeB.w, mask);
        }

        if (lane < 16) ((float4*)(sum_x + (size_t)nA * IN_DIM))[lane] = axA;
        if (lane < 8)  ((float4*)(sum_ea + (size_t)nA * EDGE_DIM))[lane] = aeA;
        if (hasB) {
            if (lane < 16) ((float4*)(sum_x + (size_t)nB * IN_DIM))[lane] = axB;
            if (lane < 8)  ((float4*)(sum_ea + (size_t)nB * EDGE_DIM))[lane] = aeB;
        }
    }
}

// Tier-3: atomic-scatter fallback.
__global__ __launch_bounds__(768) void scatter_fb_k(
    const float* __restrict__ x, const int* __restrict__ ei,
    const float* __restrict__ ea, float* sum_x, float* sum_ea, int* deg)
{
    const int t  = threadIdx.x;
    const int el = t / 96;
    const int k  = t - el * 96;
    const int e  = blockIdx.x * 8 + el;
    if (e >= N_EDGES) return;
    const int dst = ei[N_EDGES + e];
    if (k < IN_DIM) {
        const int src = ei[e];
        atomicAdd(&sum_x[dst * IN_DIM + k], x[src * IN_DIM + k]);
        if (k == 0) atomicAdd(&deg[dst], 1);
    } else {
        const int kk = k - IN_DIM;
        atomicAdd(&sum_ea[dst * EDGE_DIM + kk], ea[e * EDGE_DIM + kk]);
    }
}

// ---------------------------------------------------------------------------
extern "C" void kernel_launch(void* const* d_in, const int* in_sizes, int n_in,
                              void* d_out, int out_size, void* d_ws, size_t ws_size,
                              hipStream_t stream) {
    const float* x      = (const float*)d_in[0];
    const int*   ei     = (const int*)d_in[1];   // [2][E]
    const float* ea     = (const float*)d_in[2];
    const float* msg_w  = (const float*)d_in[3];
    const float* msg_b  = (const float*)d_in[4];
    const float* self_w = (const float*)d_in[5];
    const float* self_b = (const float*)d_in[6];

    float* out = (float*)d_out;  // doubles as sum_x accumulator

    // ws layout (elements): sum_ea[1.6M] | cnt[50k] | cur[50k] | pairs/perm | cursor
    float* sum_ea = (float*)d_ws;
    int*   cnt    = (int*)(sum_ea + (size_t)N_NODES * EDGE_DIM);
    int*   cur    = cnt + N_NODES;
    int*   idxbuf = cur + N_NODES;  // pairs (int2*N_EDGES) or perm (int*N_EDGES)
    const size_t base_elems = (size_t)N_NODES * EDGE_DIM + 2 * N_NODES;
    const size_t need_pairs = (base_elems + 2 * (size_t)N_EDGES + 2) * sizeof(int);
    const size_t need_perm  = (base_elems + (size_t)N_EDGES + 1) * sizeof(int);

    if (ws_size >= need_pairs) {
        int2* pairs  = (int2*)idxbuf;
        int*  cursor = idxbuf + 2 * (size_t)N_EDGES;
        hipMemsetAsync(cnt, 0, N_NODES * sizeof(int), stream);
        hipMemsetAsync(cursor, 0, sizeof(int), stream);

        count_k<<<(N_EDGES / 4 + 255) / 256, 256, 0, stream>>>(ei, cnt);
        alloc_k<<<(N_NODES + 255) / 256, 256, 0, stream>>>(cnt, cur, cursor);
        place_pairs_k<<<(N_EDGES / 4 + 255) / 256, 256, 0, stream>>>(ei, cur, pairs);
        aggregate_pairs_k<<<(N_NODES + 15) / 16, 256, 0, stream>>>(
            x, ea, pairs, cnt, cur, out, sum_ea);
        msg_k<<<1024, 256, 0, stream>>>(out, sum_ea, cnt, msg_w, msg_b, out);
        self_k<<<1024, 256, 0, stream>>>(x, self_w, self_b, out);
    } else if (ws_size >= need_perm) {
        int* perm   = idxbuf;
        int* cursor = idxbuf + N_EDGES;
        hipMemsetAsync(cnt, 0, N_NODES * sizeof(int), stream);
        hipMemsetAsync(cursor, 0, sizeof(int), stream);

        count_k<<<(N_EDGES / 4 + 255) / 256, 256, 0, stream>>>(ei, cnt);
        alloc_k<<<(N_NODES + 255) / 256, 256, 0, stream>>>(cnt, cur, cursor);
        place_perm_k<<<(N_EDGES / 4 + 255) / 256, 256, 0, stream>>>(ei, cur, perm);
        aggregate_perm_k<<<(N_NODES / 2 + 3) / 4, 256, 0, stream>>>(
            x, ei, ea, perm, cnt, cur, out, sum_ea);
        msg_k<<<1024, 256, 0, stream>>>(out, sum_ea, cnt, msg_w, msg_b, out);
        self_k<<<1024, 256, 0, stream>>>(x, self_w, self_b, out);
    } else {
        int* deg = cnt;
        hipMemsetAsync(d_out, 0, (size_t)N_NODES * OUT_DIM * sizeof(float), stream);
        hipMemsetAsync(d_ws, 0, (size_t)N_NODES * (EDGE_DIM + 1) * sizeof(float), stream);
        scatter_fb_k<<<(N_EDGES + 7) / 8, 768, 0, stream>>>(x, ei, ea, out, sum_ea, deg);
        msg_k<<<1024, 256, 0, stream>>>(out, sum_ea, deg, msg_w, msg_b, out);
        self_k<<<1024, 256, 0, stream>>>(x, self_w, self_b, out);
    }
}